// Round 19
// baseline (53.339 us; speedup 1.0000x reference)
//
#include <hip/hip_runtime.h>

#define HW_TOT 131072
#define IMG_W  512
#define IMG_H  256
#define KC     2048
#define MAXKP  512
#define NB     32
#define NC     768
#define CG     32
#define NCG    (NC / CG)          // 24
#define NBUCK  2048
#define NFB    4096
#define NCAND  4096
#define NSEG   8
#define SEGSZ  (HW_TOT / NSEG)    // 16384
#define SEGCAP 1024
#define VT0    0.975f
#define LSTRIDE 514
#define MPRE   1024               // NMS prefix size (fallback: 2048)

typedef float f32x4 __attribute__((ext_vector_type(4)));

// ws layout: segcnt[256] | cand[32*8*SEGCAP]
#define SEGCNT_OFF 0
#define CAND_OFF   2048

// 1024-thread exclusive block scan: 6 shfl steps + 16-entry serial, 2 barriers.
__device__ __forceinline__ int blockExclScan(int s, int tid, int* wsum)
{
    const int lane = tid & 63, wid = tid >> 6;
    int incl = s;
    #pragma unroll
    for (int d = 1; d < 64; d <<= 1) {
        int t = __shfl_up(incl, d);
        if (lane >= d) incl += t;
    }
    if (lane == 63) wsum[wid] = incl;
    __syncthreads();
    if (tid == 0) {
        int run = 0;
        #pragma unroll
        for (int w = 0; w < 16; ++w) { int c = wsum[w]; wsum[w] = run; run += c; }
    }
    __syncthreads();
    return wsum[wid] + incl - s;
}

// ---------------------------------------------------------------------------
// K_scan1: gather v >= VT0 into fixed per-(b,seg) slots.
// ---------------------------------------------------------------------------
__global__ __launch_bounds__(1024) void scan1_kernel(
    const float* __restrict__ gray,
    const float* __restrict__ mask,
    unsigned int* __restrict__ segcnt,
    unsigned long long* __restrict__ cand)
{
    const int b   = blockIdx.x >> 3;
    const int seg = blockIdx.x & 7;
    const int tid = threadIdx.x;

    __shared__ unsigned long long st[SEGCAP];
    __shared__ unsigned int lcnt;
    if (tid == 0) lcnt = 0u;
    __syncthreads();

    const float4* gi = (const float4*)(gray + (size_t)b * HW_TOT + (size_t)seg * SEGSZ);
    const float4* mi = (const float4*)(mask + (size_t)b * HW_TOT + (size_t)seg * SEGSZ);
    for (int e = tid; e < SEGSZ / 4; e += 1024) {
        float4 g = gi[e], m = mi[e];
        float vv[4] = { g.x * m.x, g.y * m.y, g.z * m.z, g.w * m.w };
        #pragma unroll
        for (int c = 0; c < 4; ++c) {
            float v = vv[c];
            if (v >= VT0) {
                unsigned int eg = (unsigned int)(seg * SEGSZ + 4 * e + c);
                unsigned int p  = atomicAdd(&lcnt, 1u);
                if (p < SEGCAP)
                    st[p] = ((unsigned long long)__float_as_uint(v) << 32) |
                            (unsigned long long)(~eg);
            }
        }
    }
    __syncthreads();
    if (tid == 0) segcnt[blockIdx.x] = lcnt;
    const unsigned int n = lcnt < SEGCAP ? lcnt : SEGCAP;
    unsigned long long* cb = cand + (size_t)blockIdx.x * SEGCAP;
    for (unsigned int i = tid; i < n; i += 1024) cb[i] = st[i];
}

// ---------------------------------------------------------------------------
// K_final: flag-check (+ fallback hist/pick/rescan) -> counting sort ->
// exact top-2048 order -> specialized M=1024 prefix NMS (1 cand/thread,
// register keep flag, syncthreads_count) -> generic M=2048 fallback if
// prefix keeps < 512 -> direct-global stable compaction.  (R12-verified)
// ---------------------------------------------------------------------------
__global__ __launch_bounds__(1024) void final_kernel(
    const float* __restrict__ gray,
    const float* __restrict__ mask,
    const unsigned long long* __restrict__ cand,
    const unsigned int* __restrict__ segcnt,
    float* __restrict__ out_kp,
    float* __restrict__ out_sc)
{
    const int b   = blockIdx.x;
    const int tid = threadIdx.x;

    __shared__ unsigned long long sorted[NCAND];   // 32KB (later: nbrList)
    __shared__ unsigned long long BUF0[NFB / 2];   // 16KB: lh/cntB -> cells
    __shared__ unsigned long long BUF1[NFB / 2];   // 16KB: startB -> cells
    __shared__ unsigned int posArr[KC];            // 8KB
    __shared__ float valArr[KC];                   // 8KB
    __shared__ unsigned int segoff[NSEG + 1];
    __shared__ int wsum[16];
    __shared__ int shT;
    __shared__ unsigned int flagSh;

    unsigned int* cntB   = (unsigned int*)BUF0;
    unsigned int* startB = (unsigned int*)BUF1;

    if (tid == 0) {
        unsigned int tot = 0; int bad = 0; unsigned int run = 0;
        #pragma unroll
        for (int sg = 0; sg < NSEG; ++sg) {
            unsigned int c = segcnt[b * NSEG + sg];
            if (c > SEGCAP) bad = 1;
            segoff[sg] = run; run += c; tot += c;
        }
        segoff[NSEG] = run;
        if (tot < KC || tot > NCAND) bad = 1;
        flagSh = (unsigned int)bad;
        shT = 0;
    }
    __syncthreads();
    const int flag = (int)flagSh;

    const float4* gi = (const float4*)(gray + (size_t)b * HW_TOT);
    const float4* mi = (const float4*)(mask + (size_t)b * HW_TOT);

    if (flag) {   // rare fallback: 2048-bin hist + threshold pick
        unsigned int* lh = cntB;
        for (int i = tid; i < NBUCK; i += 1024) lh[i] = 0u;
        __syncthreads();
        for (int e = tid; e < HW_TOT / 4; e += 1024) {
            float4 g = gi[e], m = mi[e];
            int b0 = (int)(g.x * m.x * 2048.0f); b0 = b0 > 2047 ? 2047 : b0;
            int b1 = (int)(g.y * m.y * 2048.0f); b1 = b1 > 2047 ? 2047 : b1;
            int b2 = (int)(g.z * m.z * 2048.0f); b2 = b2 > 2047 ? 2047 : b2;
            int b3 = (int)(g.w * m.w * 2048.0f); b3 = b3 > 2047 ? 2047 : b3;
            atomicAdd(&lh[b0], 1u); atomicAdd(&lh[b1], 1u);
            atomicAdd(&lh[b2], 1u); atomicAdd(&lh[b3], 1u);
        }
        __syncthreads();
        int c0v = (int)lh[2047 - 2 * tid];
        int c1v = (int)lh[2046 - 2 * tid];
        int ex  = blockExclScan(c0v + c1v, tid, wsum);
        int cmax = -1;
        if (ex + c0v >= KC)            cmax = 2047 - 2 * tid;
        else if (ex + c0v + c1v >= KC) cmax = 2046 - 2 * tid;
        if (cmax >= 0) atomicMax(&shT, cmax);
        __syncthreads();
    }
    const float lo    = flag ? (float)shT * (1.0f / 2048.0f) : VT0;   // exact
    const float scale = (float)NFB / (1.0f - lo);

    for (int i = tid; i < NFB; i += 1024) cntB[i] = 0u;
    sorted[tid] = 0ull; sorted[tid + 1024] = 0ull;
    __syncthreads();

    // ---- count pass ----
    if (!flag) {
        for (int sg = 0; sg < NSEG; ++sg) {
            const int n = (int)(segoff[sg + 1] - segoff[sg]);
            const unsigned long long* cbs = cand + (size_t)(b * NSEG + sg) * SEGCAP;
            for (int i = tid; i < n; i += 1024) {
                float v = __uint_as_float((unsigned int)(cbs[i] >> 32));
                int bk = (int)((v - lo) * scale);
                bk = bk < 0 ? 0 : (bk > NFB - 1 ? NFB - 1 : bk);
                atomicAdd(&cntB[bk], 1u);
            }
        }
    } else {
        for (int e = tid; e < HW_TOT / 4; e += 1024) {
            float4 g = gi[e], m = mi[e];
            float vv[4] = { g.x * m.x, g.y * m.y, g.z * m.z, g.w * m.w };
            #pragma unroll
            for (int c = 0; c < 4; ++c) {
                float v = vv[c];
                if (v >= lo) {
                    int bk = (int)((v - lo) * scale);
                    bk = bk < 0 ? 0 : (bk > NFB - 1 ? NFB - 1 : bk);
                    atomicAdd(&cntB[bk], 1u);
                }
            }
        }
    }
    __syncthreads();

    // ---- descending-order allocation via rev-index scan (4 bins/thread) ----
    {
        int c[4]; int s = 0;
        #pragma unroll
        for (int j = 0; j < 4; ++j) { c[j] = (int)cntB[NFB - 1 - (4 * tid + j)]; s += c[j]; }
        int ex = blockExclScan(s, tid, wsum);
        #pragma unroll
        for (int j = 0; j < 4; ++j) { startB[NFB - 1 - (4 * tid + j)] = (unsigned int)ex; ex += c[j]; }
    }
    __syncthreads();

    // ---- scatter pass (bucket-grouped; cap NCAND) ----
    if (!flag) {
        for (int sg = 0; sg < NSEG; ++sg) {
            const int n = (int)(segoff[sg + 1] - segoff[sg]);
            const unsigned long long* cbs = cand + (size_t)(b * NSEG + sg) * SEGCAP;
            for (int i = tid; i < n; i += 1024) {
                unsigned long long key = cbs[i];
                float v = __uint_as_float((unsigned int)(key >> 32));
                int bk = (int)((v - lo) * scale);
                bk = bk < 0 ? 0 : (bk > NFB - 1 ? NFB - 1 : bk);
                unsigned int p = atomicAdd(&startB[bk], 1u);
                if (p < NCAND) sorted[p] = key;
            }
        }
    } else {
        for (int e = tid; e < HW_TOT / 4; e += 1024) {
            float4 g = gi[e], m = mi[e];
            float vv[4] = { g.x * m.x, g.y * m.y, g.z * m.z, g.w * m.w };
            #pragma unroll
            for (int c = 0; c < 4; ++c) {
                float v = vv[c];
                if (v >= lo) {
                    unsigned int eg = (unsigned int)(4 * e + c);
                    int bk = (int)((v - lo) * scale);
                    bk = bk < 0 ? 0 : (bk > NFB - 1 ? NFB - 1 : bk);
                    unsigned int p = atomicAdd(&startB[bk], 1u);
                    if (p < NCAND)
                        sorted[p] = ((unsigned long long)__float_as_uint(v) << 32) |
                                    (unsigned long long)(~eg);
                }
            }
        }
    }
    __syncthreads();

    // ---- per-bucket insertion sort, descending; skip bins starting >= KC ----
    for (int k = tid; k < NFB; k += 1024) {
        int n = (int)cntB[k];
        if (n >= 2) {
            int endp = (int)startB[k];
            int s    = endp - n;
            if (s < KC) {
                int e2 = endp < NCAND ? endp : NCAND;
                for (int a = s + 1; a < e2; ++a) {
                    unsigned long long key = sorted[a];
                    int bp = a - 1;
                    while (bp >= s && sorted[bp] < key) { sorted[bp + 1] = sorted[bp]; --bp; }
                    sorted[bp + 1] = key;
                }
            }
        }
    }
    __syncthreads();

    // ---- unpack exact top-2048 ----
    for (int i = tid; i < KC; i += 1024) {
        unsigned long long key = sorted[i];
        posArr[i] = ~((unsigned int)(key & 0xFFFFFFFFull));
        valArr[i] = __uint_as_float((unsigned int)(key >> 32));
    }
    __syncthreads();   // cntB/startB/sorted dead; reuse

    unsigned int*   cellCnt   = (unsigned int*)BUF0;                 // [2048]
    unsigned int*   cellStart = cellCnt + 2048;                      // [2048]
    unsigned short* cellList  = (unsigned short*)BUF1;               // [2048]
    unsigned char*  keepA     = (unsigned char*)(cellList + 2048);   // [2048]
    unsigned char*  keepB     = keepA + KC;                          // [2048]
    unsigned char*  nbrCnt    = keepB + KC;                          // [2048]
    unsigned short* nbrList   = (unsigned short*)sorted;             // [2048*8]

    // ================= attempt 0: M = 1024, one candidate per thread ======
    int myKeep = 0;
    int usedPrefix = 1;
    {
        const int i = tid;
        const unsigned int e = posArr[i];
        const int x = (int)(e & (IMG_W - 1)), y = (int)(e >> 9);
        const int cx = (x >> 3) & 63, cy = (y >> 3) & 31;
        const int cell = cy * 64 + cx;
        const bool valid = (valArr[i] > 0.1f);

        cellCnt[tid] = 0u; cellCnt[tid + 1024] = 0u;
        __syncthreads();
        atomicAdd(&cellCnt[cell], 1u);
        __syncthreads();
        {
            int c0v = (int)cellCnt[2 * tid], c1v = (int)cellCnt[2 * tid + 1];
            int ex = blockExclScan(c0v + c1v, tid, wsum);
            cellStart[2 * tid]     = (unsigned int)ex;
            cellStart[2 * tid + 1] = (unsigned int)(ex + c0v);
        }
        __syncthreads();
        {
            unsigned int p = atomicAdd(&cellStart[cell], 1u);
            cellList[p] = (unsigned short)i;
        }
        __syncthreads();

        int n = 0;
        bool sup1 = false;
        for (int dy = -1; dy <= 1; ++dy) {
            int cyy = cy + dy; if (cyy < 0 || cyy > 31) continue;
            for (int dx = -1; dx <= 1; ++dx) {
                int cxx = cx + dx; if (cxx < 0 || cxx > 63) continue;
                int cc = cyy * 64 + cxx;
                int end = (int)cellStart[cc], num = (int)cellCnt[cc];
                for (int q = end - num; q < end; ++q) {
                    int j = (int)cellList[q];
                    if (j < i) {
                        unsigned int ej = posArr[j];
                        int ddx = x - (int)(ej & (IMG_W - 1));
                        int ddy = y - (int)(ej >> 9);
                        if (ddx * ddx + ddy * ddy < 9) {
                            if (n < 8) nbrList[i * 8 + n] = (unsigned short)j;
                            ++n;
                            sup1 = sup1 || (valArr[j] > 0.1f);
                        }
                    }
                }
            }
        }
        nbrCnt[i] = (unsigned char)(n > 8 ? 9 : n);
        int cur = (valid && !sup1) ? 1 : 0;
        keepA[i] = (unsigned char)cur;
        __syncthreads();

        unsigned char *curK = keepA, *nxtK = keepB;
        for (int it = 0; it < KC; ++it) {
            int nv = 0;
            if (valid) {
                bool sup = false;
                int nn = (int)nbrCnt[i];
                if (nn <= 8) {
                    for (int q = 0; q < nn; ++q) sup = sup || (curK[nbrList[i * 8 + q]] != 0);
                } else {
                    for (int dy = -1; dy <= 1 && !sup; ++dy) {
                        int cyy = cy + dy; if (cyy < 0 || cyy > 31) continue;
                        for (int dx = -1; dx <= 1 && !sup; ++dx) {
                            int cxx = cx + dx; if (cxx < 0 || cxx > 63) continue;
                            int cc = cyy * 64 + cxx;
                            int end = (int)cellStart[cc], num = (int)cellCnt[cc];
                            for (int q = end - num; q < end; ++q) {
                                int j = (int)cellList[q];
                                if (j < i && curK[j]) {
                                    unsigned int ej = posArr[j];
                                    int ddx = x - (int)(ej & (IMG_W - 1));
                                    int ddy = y - (int)(ej >> 9);
                                    if (ddx * ddx + ddy * ddy < 9) { sup = true; break; }
                                }
                            }
                        }
                    }
                }
                nv = sup ? 0 : 1;
            }
            nxtK[i] = (unsigned char)nv;
            int totCh = __syncthreads_count(nv != cur);
            { unsigned char* t = curK; curK = nxtK; nxtK = t; }
            cur = nv;
            if (totCh == 0) break;
        }
        myKeep = cur;

        int keeps = __syncthreads_count(myKeep);
        if (keeps < MAXKP) usedPrefix = 0;    // uniform across block
    }

    // ================= fallback attempt: M = 2048 (rare) ==================
    unsigned char* finK = keepA;
    if (!usedPrefix) {
        __syncthreads();
        for (int i = tid; i < 2048; i += 1024) cellCnt[i] = 0u;
        __syncthreads();
        for (int i = tid; i < KC; i += 1024) {
            unsigned int e = posArr[i];
            int cell = (int)((((e >> 9) >> 3) & 31u) * 64u + (((e & (IMG_W-1)) >> 3) & 63u));
            atomicAdd(&cellCnt[cell], 1u);
        }
        __syncthreads();
        {
            int c0v = (int)cellCnt[2 * tid], c1v = (int)cellCnt[2 * tid + 1];
            int ex = blockExclScan(c0v + c1v, tid, wsum);
            cellStart[2 * tid]     = (unsigned int)ex;
            cellStart[2 * tid + 1] = (unsigned int)(ex + c0v);
        }
        __syncthreads();
        for (int i = tid; i < KC; i += 1024) {
            unsigned int e = posArr[i];
            int cell = (int)((((e >> 9) >> 3) & 31u) * 64u + (((e & (IMG_W-1)) >> 3) & 63u));
            unsigned int p = atomicAdd(&cellStart[cell], 1u);
            cellList[p] = (unsigned short)i;
        }
        __syncthreads();
        for (int i = tid; i < KC; i += 1024) {
            unsigned int e = posArr[i];
            int x = (int)(e & (IMG_W - 1)), y = (int)(e >> 9);
            int cx = (x >> 3) & 63, cy = (y >> 3) & 31;
            int n = 0; bool sup1 = false;
            for (int dy = -1; dy <= 1; ++dy) {
                int cyy = cy + dy; if (cyy < 0 || cyy > 31) continue;
                for (int dx = -1; dx <= 1; ++dx) {
                    int cxx = cx + dx; if (cxx < 0 || cxx > 63) continue;
                    int cc = cyy * 64 + cxx;
                    int end = (int)cellStart[cc], num = (int)cellCnt[cc];
                    for (int q = end - num; q < end; ++q) {
                        int j = (int)cellList[q];
                        if (j < i) {
                            unsigned int ej = posArr[j];
                            int ddx = x - (int)(ej & (IMG_W - 1));
                            int ddy = y - (int)(ej >> 9);
                            if (ddx * ddx + ddy * ddy < 9) {
                                if (n < 8) nbrList[i * 8 + n] = (unsigned short)j;
                                ++n;
                                sup1 = sup1 || (valArr[j] > 0.1f);
                            }
                        }
                    }
                }
            }
            nbrCnt[i] = (unsigned char)(n > 8 ? 9 : n);
            keepA[i]  = ((valArr[i] > 0.1f) && !sup1) ? 1 : 0;
        }
        __syncthreads();
        unsigned char *curK = keepA, *nxtK = keepB;
        for (int it = 0; it < KC; ++it) {
            int localCh = 0;
            for (int i = tid; i < KC; i += 1024) {
                unsigned char c0 = curK[i];
                unsigned char nv = 0;
                if (valArr[i] > 0.1f) {
                    int nn = (int)nbrCnt[i];
                    bool sup = false;
                    if (nn <= 8) {
                        for (int q = 0; q < nn; ++q) sup = sup || (curK[nbrList[i * 8 + q]] != 0);
                    } else {
                        unsigned int e = posArr[i];
                        int x = (int)(e & (IMG_W - 1)), y = (int)(e >> 9);
                        int cx = (x >> 3) & 63, cy = (y >> 3) & 31;
                        for (int dy = -1; dy <= 1 && !sup; ++dy) {
                            int cyy = cy + dy; if (cyy < 0 || cyy > 31) continue;
                            for (int dx = -1; dx <= 1 && !sup; ++dx) {
                                int cxx = cx + dx; if (cxx < 0 || cxx > 63) continue;
                                int cc = cyy * 64 + cxx;
                                int end = (int)cellStart[cc], num = (int)cellCnt[cc];
                                for (int q = end - num; q < end; ++q) {
                                    int j = (int)cellList[q];
                                    if (j < i && curK[j]) {
                                        unsigned int ej = posArr[j];
                                        int ddx = x - (int)(ej & (IMG_W - 1));
                                        int ddy = y - (int)(ej >> 9);
                                        if (ddx * ddx + ddy * ddy < 9) { sup = true; break; }
                                    }
                                }
                            }
                        }
                    }
                    nv = sup ? 0 : 1;
                }
                nxtK[i] = nv;
                localCh |= (nv != c0);
            }
            int totCh = __syncthreads_count(localCh);
            { unsigned char* t = curK; curK = nxtK; nxtK = t; }
            if (totCh == 0) break;
        }
        finK = curK;
    }

    // ---- stable compaction, direct-to-global ----
    float* kpb = out_kp + (size_t)b * (MAXKP * 2);
    float* scb = out_sc + (size_t)b * MAXKP;

    int a0, a1, i0, i1;
    if (usedPrefix) { i0 = tid;     i1 = -1;          a0 = myKeep;         a1 = 0; }
    else            { i0 = 2 * tid; i1 = 2 * tid + 1; a0 = (int)finK[i0]; a1 = (int)finK[i1]; }
    int ex = blockExclScan(a0 + a1, tid, wsum);
    int r0 = ex, r1 = ex + a0;

    if (tid < MAXKP) { kpb[2 * tid] = 0.f; kpb[2 * tid + 1] = 0.f; scb[tid] = 0.f; }
    __syncthreads();
    if (a0 && r0 < MAXKP) {
        unsigned int e = posArr[i0];
        kpb[2 * r0] = (float)(e & (IMG_W - 1)); kpb[2 * r0 + 1] = (float)(e >> 9);
        scb[r0] = valArr[i0];
    }
    if (a1 && r1 < MAXKP) {
        unsigned int e = posArr[i1];
        kpb[2 * r1] = (float)(e & (IMG_W - 1)); kpb[2 * r1 + 1] = (float)(e >> 9);
        scb[r1] = valArr[i1];
    }
}

// ---------------------------------------------------------------------------
// K_sample: bilinear descriptors. CG=32 planes, 1024 threads; 8-lane cluster
// writes one aligned 128B line per keypoint. Nontemporal loads (fm read
// once) + nontemporal stores (desc write once). kp load hoisted.
// ---------------------------------------------------------------------------
__global__ __launch_bounds__(1024) void sample_kernel(
    const float* __restrict__ fm,
    const float* __restrict__ kp,
    float* __restrict__ out_desc)
{
    const int blk = blockIdx.x;
    const int b   = blk / NCG;
    const int cg  = blk % NCG;
    const int c0  = cg * CG;
    const int tid = threadIdx.x;

    __shared__ float L[CG * LSTRIDE];          // ~66KB
    __shared__ float sxl[MAXKP], syl[MAXKP];   // 4KB

    // kp load issued first; latency hides under the 16 staged fm loads
    float2 k2;
    if (tid < MAXKP) k2 = ((const float2*)kp)[(size_t)b * MAXKP + tid];

    const f32x4* src = (const f32x4*)(fm + (size_t)b * NC * 512 + (size_t)c0 * 512);
    #pragma unroll
    for (int it = 0; it < 4; ++it) {
        int e  = tid + it * 1024;              // < 4096
        int cc = e >> 7, j = e & 127;
        f32x4 v = __builtin_nontemporal_load(&src[cc * 128 + j]);
        float* dst = &L[cc * LSTRIDE + 4 * j];
        dst[0] = v[0]; dst[1] = v[1]; dst[2] = v[2]; dst[3] = v[3];
    }
    if (tid < MAXKP) { sxl[tid] = k2.x; syl[tid] = k2.y; }
    __syncthreads();

    const int chunk = tid & 7;                 // 4 channels each
    float* outb = out_desc + (size_t)b * MAXKP * NC + c0 + 4 * chunk;
    #pragma unroll
    for (int it = 0; it < 4; ++it) {
        const int p = it * 128 + (tid >> 3);
        float x = sxl[p], y = syl[p];
        float fx = x * (31.0f / 512.0f);
        float fy = y * (15.0f / 256.0f);
        float x0f = floorf(fx), y0f = floorf(fy);
        float wx = fx - x0f, wy = fy - y0f;
        int x0 = (int)fminf(x0f,       31.f);
        int x1 = (int)fminf(x0f + 1.f, 31.f);
        int y0 = (int)fminf(y0f,       15.f);
        int y1 = (int)fminf(y0f + 1.f, 15.f);
        float w00 = (1.f - wx) * (1.f - wy);
        float w01 = wx * (1.f - wy);
        float w10 = (1.f - wx) * wy;
        float w11 = wx * wy;
        int o00 = y0 * 32 + x0, o01 = y0 * 32 + x1;
        int o10 = y1 * 32 + x0, o11 = y1 * 32 + x1;

        f32x4 r;
        #pragma unroll
        for (int u = 0; u < 4; ++u) {
            const float* Lc = &L[(4 * chunk + u) * LSTRIDE];
            r[u] = Lc[o00] * w00 + Lc[o01] * w01 + Lc[o10] * w10 + Lc[o11] * w11;
        }
        __builtin_nontemporal_store(r, (f32x4*)(outb + (size_t)p * NC));
    }
}

extern "C" void kernel_launch(void* const* d_in, const int* in_sizes, int n_in,
                              void* d_out, int out_size, void* d_ws, size_t ws_size,
                              hipStream_t stream)
{
    const float* gray = (const float*)d_in[0];
    const float* mask = (const float*)d_in[1];
    const float* fm   = (const float*)d_in[2];

    float* out      = (float*)d_out;
    float* out_kp   = out;
    float* out_sc   = out + (size_t)NB * MAXKP * 2;
    float* out_desc = out + (size_t)NB * MAXKP * 2 + (size_t)NB * MAXKP;

    unsigned int*       segcnt = (unsigned int*)((char*)d_ws + SEGCNT_OFF);
    unsigned long long* cand   = (unsigned long long*)((char*)d_ws + CAND_OFF);

    scan1_kernel <<<NB * NSEG, 1024, 0, stream>>>(gray, mask, segcnt, cand);
    final_kernel <<<NB,        1024, 0, stream>>>(gray, mask, cand, segcnt,
                                                  out_kp, out_sc);
    sample_kernel<<<NB * NCG,  1024, 0, stream>>>(fm, out_kp, out_desc);
}

// Round 20
// 50.365 us; speedup vs baseline: 1.0590x; 1.0590x over previous
//
#include <hip/hip_runtime.h>

#define HW_TOT 131072
#define IMG_W  512
#define IMG_H  256
#define KC     2048
#define MAXKP  512
#define NB     32
#define NC     768
#define CG     32
#define NCG    (NC / CG)          // 24
#define NBUCK  2048
#define NFB    4096
#define NCAND  4096
#define NSEG   8
#define SEGSZ  (HW_TOT / NSEG)    // 16384
#define SEGCAP 1024
#define VT0    0.975f
#define LSTRIDE 514
#define MPRE   1024               // NMS prefix size (fallback: 2048)

typedef float f32x4 __attribute__((ext_vector_type(4)));

// ws layout: segcnt[256] | cand[32*8*SEGCAP]
#define SEGCNT_OFF 0
#define CAND_OFF   2048

// 1024-thread exclusive block scan: 6 shfl steps + 16-entry serial, 2 barriers.
__device__ __forceinline__ int blockExclScan(int s, int tid, int* wsum)
{
    const int lane = tid & 63, wid = tid >> 6;
    int incl = s;
    #pragma unroll
    for (int d = 1; d < 64; d <<= 1) {
        int t = __shfl_up(incl, d);
        if (lane >= d) incl += t;
    }
    if (lane == 63) wsum[wid] = incl;
    __syncthreads();
    if (tid == 0) {
        int run = 0;
        #pragma unroll
        for (int w = 0; w < 16; ++w) { int c = wsum[w]; wsum[w] = run; run += c; }
    }
    __syncthreads();
    return wsum[wid] + incl - s;
}

// ---------------------------------------------------------------------------
// K_scan1: gather v >= VT0 into fixed per-(b,seg) slots.
// ---------------------------------------------------------------------------
__global__ __launch_bounds__(1024) void scan1_kernel(
    const float* __restrict__ gray,
    const float* __restrict__ mask,
    unsigned int* __restrict__ segcnt,
    unsigned long long* __restrict__ cand)
{
    const int b   = blockIdx.x >> 3;
    const int seg = blockIdx.x & 7;
    const int tid = threadIdx.x;

    __shared__ unsigned long long st[SEGCAP];
    __shared__ unsigned int lcnt;
    if (tid == 0) lcnt = 0u;
    __syncthreads();

    const float4* gi = (const float4*)(gray + (size_t)b * HW_TOT + (size_t)seg * SEGSZ);
    const float4* mi = (const float4*)(mask + (size_t)b * HW_TOT + (size_t)seg * SEGSZ);
    for (int e = tid; e < SEGSZ / 4; e += 1024) {
        float4 g = gi[e], m = mi[e];
        float vv[4] = { g.x * m.x, g.y * m.y, g.z * m.z, g.w * m.w };
        #pragma unroll
        for (int c = 0; c < 4; ++c) {
            float v = vv[c];
            if (v >= VT0) {
                unsigned int eg = (unsigned int)(seg * SEGSZ + 4 * e + c);
                unsigned int p  = atomicAdd(&lcnt, 1u);
                if (p < SEGCAP)
                    st[p] = ((unsigned long long)__float_as_uint(v) << 32) |
                            (unsigned long long)(~eg);
            }
        }
    }
    __syncthreads();
    if (tid == 0) segcnt[blockIdx.x] = lcnt;
    const unsigned int n = lcnt < SEGCAP ? lcnt : SEGCAP;
    unsigned long long* cb = cand + (size_t)blockIdx.x * SEGCAP;
    for (unsigned int i = tid; i < n; i += 1024) cb[i] = st[i];
}

// ---------------------------------------------------------------------------
// K_final: flag-check (+ fallback hist/pick/rescan) -> counting sort ->
// exact top-2048 order -> specialized M=1024 prefix NMS (1 cand/thread,
// register keep flag, syncthreads_count) -> generic M=2048 fallback if
// prefix keeps < 512 -> direct-global stable compaction.
// ---------------------------------------------------------------------------
__global__ __launch_bounds__(1024) void final_kernel(
    const float* __restrict__ gray,
    const float* __restrict__ mask,
    const unsigned long long* __restrict__ cand,
    const unsigned int* __restrict__ segcnt,
    float* __restrict__ out_kp,
    float* __restrict__ out_sc)
{
    const int b   = blockIdx.x;
    const int tid = threadIdx.x;

    __shared__ unsigned long long sorted[NCAND];   // 32KB (later: nbrList)
    __shared__ unsigned long long BUF0[NFB / 2];   // 16KB: lh/cntB -> cells
    __shared__ unsigned long long BUF1[NFB / 2];   // 16KB: startB -> cells
    __shared__ unsigned int posArr[KC];            // 8KB
    __shared__ float valArr[KC];                   // 8KB
    __shared__ unsigned int segoff[NSEG + 1];
    __shared__ int wsum[16];
    __shared__ int shT;
    __shared__ unsigned int flagSh;

    unsigned int* cntB   = (unsigned int*)BUF0;
    unsigned int* startB = (unsigned int*)BUF1;

    if (tid == 0) {
        unsigned int tot = 0; int bad = 0; unsigned int run = 0;
        #pragma unroll
        for (int sg = 0; sg < NSEG; ++sg) {
            unsigned int c = segcnt[b * NSEG + sg];
            if (c > SEGCAP) bad = 1;
            segoff[sg] = run; run += c; tot += c;
        }
        segoff[NSEG] = run;
        if (tot < KC || tot > NCAND) bad = 1;
        flagSh = (unsigned int)bad;
        shT = 0;
    }
    __syncthreads();
    const int flag = (int)flagSh;

    const float4* gi = (const float4*)(gray + (size_t)b * HW_TOT);
    const float4* mi = (const float4*)(mask + (size_t)b * HW_TOT);

    if (flag) {   // rare fallback: 2048-bin hist + threshold pick
        unsigned int* lh = cntB;
        for (int i = tid; i < NBUCK; i += 1024) lh[i] = 0u;
        __syncthreads();
        for (int e = tid; e < HW_TOT / 4; e += 1024) {
            float4 g = gi[e], m = mi[e];
            int b0 = (int)(g.x * m.x * 2048.0f); b0 = b0 > 2047 ? 2047 : b0;
            int b1 = (int)(g.y * m.y * 2048.0f); b1 = b1 > 2047 ? 2047 : b1;
            int b2 = (int)(g.z * m.z * 2048.0f); b2 = b2 > 2047 ? 2047 : b2;
            int b3 = (int)(g.w * m.w * 2048.0f); b3 = b3 > 2047 ? 2047 : b3;
            atomicAdd(&lh[b0], 1u); atomicAdd(&lh[b1], 1u);
            atomicAdd(&lh[b2], 1u); atomicAdd(&lh[b3], 1u);
        }
        __syncthreads();
        int c0v = (int)lh[2047 - 2 * tid];
        int c1v = (int)lh[2046 - 2 * tid];
        int ex  = blockExclScan(c0v + c1v, tid, wsum);
        int cmax = -1;
        if (ex + c0v >= KC)            cmax = 2047 - 2 * tid;
        else if (ex + c0v + c1v >= KC) cmax = 2046 - 2 * tid;
        if (cmax >= 0) atomicMax(&shT, cmax);
        __syncthreads();
    }
    const float lo    = flag ? (float)shT * (1.0f / 2048.0f) : VT0;   // exact
    const float scale = (float)NFB / (1.0f - lo);

    // zero bins AND pre-zero sorted[0..KC) (phantom safety) in one phase
    for (int i = tid; i < NFB; i += 1024) cntB[i] = 0u;
    sorted[tid] = 0ull; sorted[tid + 1024] = 0ull;
    __syncthreads();

    // ---- count pass ----
    if (!flag) {
        for (int sg = 0; sg < NSEG; ++sg) {
            const int n = (int)(segoff[sg + 1] - segoff[sg]);
            const unsigned long long* cbs = cand + (size_t)(b * NSEG + sg) * SEGCAP;
            for (int i = tid; i < n; i += 1024) {
                float v = __uint_as_float((unsigned int)(cbs[i] >> 32));
                int bk = (int)((v - lo) * scale);
                bk = bk < 0 ? 0 : (bk > NFB - 1 ? NFB - 1 : bk);
                atomicAdd(&cntB[bk], 1u);
            }
        }
    } else {
        for (int e = tid; e < HW_TOT / 4; e += 1024) {
            float4 g = gi[e], m = mi[e];
            float vv[4] = { g.x * m.x, g.y * m.y, g.z * m.z, g.w * m.w };
            #pragma unroll
            for (int c = 0; c < 4; ++c) {
                float v = vv[c];
                if (v >= lo) {
                    int bk = (int)((v - lo) * scale);
                    bk = bk < 0 ? 0 : (bk > NFB - 1 ? NFB - 1 : bk);
                    atomicAdd(&cntB[bk], 1u);
                }
            }
        }
    }
    __syncthreads();

    // ---- descending-order allocation via rev-index scan (4 bins/thread) ----
    {
        int c[4]; int s = 0;
        #pragma unroll
        for (int j = 0; j < 4; ++j) { c[j] = (int)cntB[NFB - 1 - (4 * tid + j)]; s += c[j]; }
        int ex = blockExclScan(s, tid, wsum);
        #pragma unroll
        for (int j = 0; j < 4; ++j) { startB[NFB - 1 - (4 * tid + j)] = (unsigned int)ex; ex += c[j]; }
    }
    __syncthreads();

    // ---- scatter pass (bucket-grouped; cap NCAND) ----
    if (!flag) {
        for (int sg = 0; sg < NSEG; ++sg) {
            const int n = (int)(segoff[sg + 1] - segoff[sg]);
            const unsigned long long* cbs = cand + (size_t)(b * NSEG + sg) * SEGCAP;
            for (int i = tid; i < n; i += 1024) {
                unsigned long long key = cbs[i];
                float v = __uint_as_float((unsigned int)(key >> 32));
                int bk = (int)((v - lo) * scale);
                bk = bk < 0 ? 0 : (bk > NFB - 1 ? NFB - 1 : bk);
                unsigned int p = atomicAdd(&startB[bk], 1u);
                if (p < NCAND) sorted[p] = key;
            }
        }
    } else {
        for (int e = tid; e < HW_TOT / 4; e += 1024) {
            float4 g = gi[e], m = mi[e];
            float vv[4] = { g.x * m.x, g.y * m.y, g.z * m.z, g.w * m.w };
            #pragma unroll
            for (int c = 0; c < 4; ++c) {
                float v = vv[c];
                if (v >= lo) {
                    unsigned int eg = (unsigned int)(4 * e + c);
                    int bk = (int)((v - lo) * scale);
                    bk = bk < 0 ? 0 : (bk > NFB - 1 ? NFB - 1 : bk);
                    unsigned int p = atomicAdd(&startB[bk], 1u);
                    if (p < NCAND)
                        sorted[p] = ((unsigned long long)__float_as_uint(v) << 32) |
                                    (unsigned long long)(~eg);
                }
            }
        }
    }
    __syncthreads();

    // ---- per-bucket insertion sort, descending; skip bins starting >= KC ----
    for (int k = tid; k < NFB; k += 1024) {
        int n = (int)cntB[k];
        if (n >= 2) {
            int endp = (int)startB[k];
            int s    = endp - n;
            if (s < KC) {
                int e2 = endp < NCAND ? endp : NCAND;
                for (int a = s + 1; a < e2; ++a) {
                    unsigned long long key = sorted[a];
                    int bp = a - 1;
                    while (bp >= s && sorted[bp] < key) { sorted[bp + 1] = sorted[bp]; --bp; }
                    sorted[bp + 1] = key;
                }
            }
        }
    }
    __syncthreads();

    // ---- unpack exact top-2048 ----
    for (int i = tid; i < KC; i += 1024) {
        unsigned long long key = sorted[i];
        posArr[i] = ~((unsigned int)(key & 0xFFFFFFFFull));
        valArr[i] = __uint_as_float((unsigned int)(key >> 32));
    }
    __syncthreads();   // cntB/startB/sorted dead; reuse

    unsigned int*   cellCnt   = (unsigned int*)BUF0;                 // [2048]
    unsigned int*   cellStart = cellCnt + 2048;                      // [2048]
    unsigned short* cellList  = (unsigned short*)BUF1;               // [2048]
    unsigned char*  keepA     = (unsigned char*)(cellList + 2048);   // [2048]
    unsigned char*  keepB     = keepA + KC;                          // [2048]
    unsigned char*  nbrCnt    = keepB + KC;                          // [2048]
    unsigned short* nbrList   = (unsigned short*)sorted;             // [2048*8]

    // ================= attempt 0: M = 1024, one candidate per thread ======
    int myKeep = 0;           // register keep flag for candidate i = tid
    int usedPrefix = 1;

    {
        const int i = tid;
        const unsigned int e = posArr[i];
        const int x = (int)(e & (IMG_W - 1)), y = (int)(e >> 9);
        const int cx = (x >> 3) & 63, cy = (y >> 3) & 31;
        const int cell = cy * 64 + cx;
        const bool valid = (valArr[i] > 0.1f);

        cellCnt[tid] = 0u; cellCnt[tid + 1024] = 0u;
        __syncthreads();
        atomicAdd(&cellCnt[cell], 1u);
        __syncthreads();
        {
            int c0v = (int)cellCnt[2 * tid], c1v = (int)cellCnt[2 * tid + 1];
            int ex = blockExclScan(c0v + c1v, tid, wsum);
            cellStart[2 * tid]     = (unsigned int)ex;
            cellStart[2 * tid + 1] = (unsigned int)(ex + c0v);
        }
        __syncthreads();
        {
            unsigned int p = atomicAdd(&cellStart[cell], 1u);
            cellList[p] = (unsigned short)i;
        }
        __syncthreads();

        // earlier-neighbor list + fused sweep 1
        int n = 0;
        bool sup1 = false;
        for (int dy = -1; dy <= 1; ++dy) {
            int cyy = cy + dy; if (cyy < 0 || cyy > 31) continue;
            for (int dx = -1; dx <= 1; ++dx) {
                int cxx = cx + dx; if (cxx < 0 || cxx > 63) continue;
                int cc = cyy * 64 + cxx;
                int end = (int)cellStart[cc], num = (int)cellCnt[cc];
                for (int q = end - num; q < end; ++q) {
                    int j = (int)cellList[q];
                    if (j < i) {
                        unsigned int ej = posArr[j];
                        int ddx = x - (int)(ej & (IMG_W - 1));
                        int ddy = y - (int)(ej >> 9);
                        if (ddx * ddx + ddy * ddy < 9) {
                            if (n < 8) nbrList[i * 8 + n] = (unsigned short)j;
                            ++n;
                            sup1 = sup1 || (valArr[j] > 0.1f);
                        }
                    }
                }
            }
        }
        nbrCnt[i] = (unsigned char)(n > 8 ? 9 : n);
        int cur = (valid && !sup1) ? 1 : 0;
        keepA[i] = (unsigned char)cur;
        __syncthreads();

        // Jacobi to the (unique) greedy fixed point
        unsigned char *curK = keepA, *nxtK = keepB;
        for (int it = 0; it < KC; ++it) {
            int nv = 0;
            if (valid) {
                bool sup = false;
                int nn = (int)nbrCnt[i];
                if (nn <= 8) {
                    for (int q = 0; q < nn; ++q) sup = sup || (curK[nbrList[i * 8 + q]] != 0);
                } else {
                    for (int dy = -1; dy <= 1 && !sup; ++dy) {
                        int cyy = cy + dy; if (cyy < 0 || cyy > 31) continue;
                        for (int dx = -1; dx <= 1 && !sup; ++dx) {
                            int cxx = cx + dx; if (cxx < 0 || cxx > 63) continue;
                            int cc = cyy * 64 + cxx;
                            int end = (int)cellStart[cc], num = (int)cellCnt[cc];
                            for (int q = end - num; q < end; ++q) {
                                int j = (int)cellList[q];
                                if (j < i && curK[j]) {
                                    unsigned int ej = posArr[j];
                                    int ddx = x - (int)(ej & (IMG_W - 1));
                                    int ddy = y - (int)(ej >> 9);
                                    if (ddx * ddx + ddy * ddy < 9) { sup = true; break; }
                                }
                            }
                        }
                    }
                }
                nv = sup ? 0 : 1;
            }
            nxtK[i] = (unsigned char)nv;
            int totCh = __syncthreads_count(nv != cur);
            { unsigned char* t = curK; curK = nxtK; nxtK = t; }
            cur = nv;
            if (totCh == 0) break;
        }
        myKeep = cur;

        int keeps = __syncthreads_count(myKeep);
        if (keeps < MAXKP) usedPrefix = 0;    // uniform across block
    }

    // ================= fallback attempt: M = 2048 (rare) ==================
    unsigned char* finK = keepA;   // which array holds final flags (fallback)
    if (!usedPrefix) {
        __syncthreads();
        for (int i = tid; i < 2048; i += 1024) cellCnt[i] = 0u;
        __syncthreads();
        for (int i = tid; i < KC; i += 1024) {
            unsigned int e = posArr[i];
            int cell = (int)((((e >> 9) >> 3) & 31u) * 64u + (((e & (IMG_W-1)) >> 3) & 63u));
            atomicAdd(&cellCnt[cell], 1u);
        }
        __syncthreads();
        {
            int c0v = (int)cellCnt[2 * tid], c1v = (int)cellCnt[2 * tid + 1];
            int ex = blockExclScan(c0v + c1v, tid, wsum);
            cellStart[2 * tid]     = (unsigned int)ex;
            cellStart[2 * tid + 1] = (unsigned int)(ex + c0v);
        }
        __syncthreads();
        for (int i = tid; i < KC; i += 1024) {
            unsigned int e = posArr[i];
            int cell = (int)((((e >> 9) >> 3) & 31u) * 64u + (((e & (IMG_W-1)) >> 3) & 63u));
            unsigned int p = atomicAdd(&cellStart[cell], 1u);
            cellList[p] = (unsigned short)i;
        }
        __syncthreads();
        for (int i = tid; i < KC; i += 1024) {
            unsigned int e = posArr[i];
            int x = (int)(e & (IMG_W - 1)), y = (int)(e >> 9);
            int cx = (x >> 3) & 63, cy = (y >> 3) & 31;
            int n = 0; bool sup1 = false;
            for (int dy = -1; dy <= 1; ++dy) {
                int cyy = cy + dy; if (cyy < 0 || cyy > 31) continue;
                for (int dx = -1; dx <= 1; ++dx) {
                    int cxx = cx + dx; if (cxx < 0 || cxx > 63) continue;
                    int cc = cyy * 64 + cxx;
                    int end = (int)cellStart[cc], num = (int)cellCnt[cc];
                    for (int q = end - num; q < end; ++q) {
                        int j = (int)cellList[q];
                        if (j < i) {
                            unsigned int ej = posArr[j];
                            int ddx = x - (int)(ej & (IMG_W - 1));
                            int ddy = y - (int)(ej >> 9);
                            if (ddx * ddx + ddy * ddy < 9) {
                                if (n < 8) nbrList[i * 8 + n] = (unsigned short)j;
                                ++n;
                                sup1 = sup1 || (valArr[j] > 0.1f);
                            }
                        }
                    }
                }
            }
            nbrCnt[i] = (unsigned char)(n > 8 ? 9 : n);
            keepA[i]  = ((valArr[i] > 0.1f) && !sup1) ? 1 : 0;
        }
        __syncthreads();
        unsigned char *curK = keepA, *nxtK = keepB;
        for (int it = 0; it < KC; ++it) {
            int localCh = 0;
            for (int i = tid; i < KC; i += 1024) {
                unsigned char c0 = curK[i];
                unsigned char nv = 0;
                if (valArr[i] > 0.1f) {
                    int nn = (int)nbrCnt[i];
                    bool sup = false;
                    if (nn <= 8) {
                        for (int q = 0; q < nn; ++q) sup = sup || (curK[nbrList[i * 8 + q]] != 0);
                    } else {
                        unsigned int e = posArr[i];
                        int x = (int)(e & (IMG_W - 1)), y = (int)(e >> 9);
                        int cx = (x >> 3) & 63, cy = (y >> 3) & 31;
                        for (int dy = -1; dy <= 1 && !sup; ++dy) {
                            int cyy = cy + dy; if (cyy < 0 || cyy > 31) continue;
                            for (int dx = -1; dx <= 1 && !sup; ++dx) {
                                int cxx = cx + dx; if (cxx < 0 || cxx > 63) continue;
                                int cc = cyy * 64 + cxx;
                                int end = (int)cellStart[cc], num = (int)cellCnt[cc];
                                for (int q = end - num; q < end; ++q) {
                                    int j = (int)cellList[q];
                                    if (j < i && curK[j]) {
                                        unsigned int ej = posArr[j];
                                        int ddx = x - (int)(ej & (IMG_W - 1));
                                        int ddy = y - (int)(ej >> 9);
                                        if (ddx * ddx + ddy * ddy < 9) { sup = true; break; }
                                    }
                                }
                            }
                        }
                    }
                    nv = sup ? 0 : 1;
                }
                nxtK[i] = nv;
                localCh |= (nv != c0);
            }
            int totCh = __syncthreads_count(localCh);
            { unsigned char* t = curK; curK = nxtK; nxtK = t; }
            if (totCh == 0) break;
        }
        finK = curK;
    }

    // ---- stable compaction, direct-to-global ----
    float* kpb = out_kp + (size_t)b * (MAXKP * 2);
    float* scb = out_sc + (size_t)b * MAXKP;

    int a0, a1, i0, i1;
    if (usedPrefix) { i0 = tid;     i1 = -1;          a0 = myKeep;         a1 = 0; }
    else            { i0 = 2 * tid; i1 = 2 * tid + 1; a0 = (int)finK[i0]; a1 = (int)finK[i1]; }
    int ex = blockExclScan(a0 + a1, tid, wsum);
    int r0 = ex, r1 = ex + a0;

    if (tid < MAXKP) { kpb[2 * tid] = 0.f; kpb[2 * tid + 1] = 0.f; scb[tid] = 0.f; }
    __syncthreads();
    if (a0 && r0 < MAXKP) {
        unsigned int e = posArr[i0];
        kpb[2 * r0] = (float)(e & (IMG_W - 1)); kpb[2 * r0 + 1] = (float)(e >> 9);
        scb[r0] = valArr[i0];
    }
    if (a1 && r1 < MAXKP) {
        unsigned int e = posArr[i1];
        kpb[2 * r1] = (float)(e & (IMG_W - 1)); kpb[2 * r1 + 1] = (float)(e >> 9);
        scb[r1] = valArr[i1];
    }
}

// ---------------------------------------------------------------------------
// K_sample: bilinear descriptors. CG=32 planes, 1024 threads; an 8-lane
// cluster writes one aligned 128B line per keypoint; nontemporal stores.
// ---------------------------------------------------------------------------
__global__ __launch_bounds__(1024) void sample_kernel(
    const float* __restrict__ fm,
    const float* __restrict__ kp,
    float* __restrict__ out_desc)
{
    const int blk = blockIdx.x;
    const int b   = blk / NCG;
    const int cg  = blk % NCG;
    const int c0  = cg * CG;
    const int tid = threadIdx.x;

    __shared__ float L[CG * LSTRIDE];          // ~66KB
    __shared__ float sxl[MAXKP], syl[MAXKP];   // 4KB

    const float4* src = (const float4*)(fm + (size_t)b * NC * 512 + (size_t)c0 * 512);
    #pragma unroll
    for (int it = 0; it < 4; ++it) {
        int e  = tid + it * 1024;              // < 4096
        int cc = e >> 7, j = e & 127;
        float4 v = src[cc * 128 + j];
        float* dst = &L[cc * LSTRIDE + 4 * j];
        *(float2*)(dst)     = make_float2(v.x, v.y);
        *(float2*)(dst + 2) = make_float2(v.z, v.w);
    }
    if (tid < MAXKP) {
        float2 k2 = ((const float2*)kp)[(size_t)b * MAXKP + tid];
        sxl[tid] = k2.x; syl[tid] = k2.y;
    }
    __syncthreads();

    const int chunk = tid & 7;                 // 4 channels each
    float* outb = out_desc + (size_t)b * MAXKP * NC + c0 + 4 * chunk;
    #pragma unroll
    for (int it = 0; it < 4; ++it) {
        const int p = it * 128 + (tid >> 3);
        float x = sxl[p], y = syl[p];
        float fx = x * (31.0f / 512.0f);
        float fy = y * (15.0f / 256.0f);
        float x0f = floorf(fx), y0f = floorf(fy);
        float wx = fx - x0f, wy = fy - y0f;
        int x0 = (int)fminf(x0f,       31.f);
        int x1 = (int)fminf(x0f + 1.f, 31.f);
        int y0 = (int)fminf(y0f,       15.f);
        int y1 = (int)fminf(y0f + 1.f, 15.f);
        float w00 = (1.f - wx) * (1.f - wy);
        float w01 = wx * (1.f - wy);
        float w10 = (1.f - wx) * wy;
        float w11 = wx * wy;
        int o00 = y0 * 32 + x0, o01 = y0 * 32 + x1;
        int o10 = y1 * 32 + x0, o11 = y1 * 32 + x1;

        f32x4 r;
        #pragma unroll
        for (int u = 0; u < 4; ++u) {
            const float* Lc = &L[(4 * chunk + u) * LSTRIDE];
            r[u] = Lc[o00] * w00 + Lc[o01] * w01 + Lc[o10] * w10 + Lc[o11] * w11;
        }
        __builtin_nontemporal_store(r, (f32x4*)(outb + (size_t)p * NC));
    }
}

extern "C" void kernel_launch(void* const* d_in, const int* in_sizes, int n_in,
                              void* d_out, int out_size, void* d_ws, size_t ws_size,
                              hipStream_t stream)
{
    const float* gray = (const float*)d_in[0];
    const float* mask = (const float*)d_in[1];
    const float* fm   = (const float*)d_in[2];

    float* out      = (float*)d_out;
    float* out_kp   = out;
    float* out_sc   = out + (size_t)NB * MAXKP * 2;
    float* out_desc = out + (size_t)NB * MAXKP * 2 + (size_t)NB * MAXKP;

    unsigned int*       segcnt = (unsigned int*)((char*)d_ws + SEGCNT_OFF);
    unsigned long long* cand   = (unsigned long long*)((char*)d_ws + CAND_OFF);

    scan1_kernel <<<NB * NSEG, 1024, 0, stream>>>(gray, mask, segcnt, cand);
    final_kernel <<<NB,        1024, 0, stream>>>(gray, mask, cand, segcnt,
                                                  out_kp, out_sc);
    sample_kernel<<<NB * NCG,  1024, 0, stream>>>(fm, out_kp, out_desc);
}